// Round 6
// baseline (392.149 us; speedup 1.0000x reference)
//
#include <hip/hip_runtime.h>
#include <hip/hip_fp16.h>
#include <math.h>

#define NN   50000
#define EE   800000
#define INF  512
#define HIDF 256
#define OUTF 64
#define MTILES (NN/16)   // 3125

using half8  = __attribute__((ext_vector_type(8))) _Float16;
using half2v = __attribute__((ext_vector_type(2))) _Float16;
using f32x4  = __attribute__((ext_vector_type(4))) float;

#if __has_builtin(__builtin_amdgcn_fdot2)
#define HAS_DOT2 1
#else
#define HAS_DOT2 0
#endif

// ---- fused prep: row_ptr (blocks 0..195) | W1 pack (196..707) | W2^T (708..771) ----
__global__ void k_prep(const int* __restrict__ a_row, int* __restrict__ row_ptr,
                       const float* __restrict__ W1, _Float16* __restrict__ W1p,
                       const float* __restrict__ W2, _Float16* __restrict__ W2T){
  int b = blockIdx.x, tid = threadIdx.x;
  if (b < 196){
    int i = b * 256 + tid;
    if (i > NN) return;
    int lo = 0, hi = EE;
    while (lo < hi){ int mid = (lo + hi) >> 1; if (a_row[mid] < i) lo = mid + 1; else hi = mid; }
    row_ptr[i] = lo;
  } else if (b < 708){
    int idx = (b - 196) * 256 + tid;        // 512*256 elements
    int k = idx >> 8, col = idx & 255;
    int kk = k >> 5, k2 = k & 31;
    W1p[((kk << 8) + col) * 32 + k2] = (_Float16)W1[idx];
  } else {
    int idx = (b - 708) * 256 + tid;        // 256*64 elements
    int k = idx >> 6, n = idx & 63;
    W2T[n * HIDF + k] = (_Float16)W2[idx];
  }
}

// ---------------- GEMM1: XW1s (8-sliced f16) = X[NN,INF] @ W1 ----------------
// barrier-free: wave = 32 rows x 256 cols, f16 MFMA, B-frags from global (L1/L2).
__global__ __launch_bounds__(128) void k_gemm1(const float* __restrict__ X,
                                               const _Float16* __restrict__ W1p,
                                               _Float16* __restrict__ XW1s){
  int wave = threadIdx.x >> 6, lane = threadIdx.x & 63;
  int l16 = lane & 15, quad = lane >> 4;
  int m0 = blockIdx.x * 64 + wave * 32;
  int r0 = min(m0 + l16, NN - 1);             // clamp reads; stores are guarded
  int r1 = min(m0 + 16 + l16, NN - 1);
  const float* arow0 = X + (size_t)r0 * INF + quad * 8;
  const float* arow1 = X + (size_t)r1 * INF + quad * 8;

  f32x4 acc0[16], acc1[16];
  #pragma unroll
  for (int t = 0; t < 16; t++){ acc0[t] = (f32x4){0.f,0.f,0.f,0.f}; acc1[t] = (f32x4){0.f,0.f,0.f,0.f}; }

  for (int kk = 0; kk < INF/32; kk++){
    const float4* ap0 = (const float4*)(arow0 + kk * 32);
    const float4* ap1 = (const float4*)(arow1 + kk * 32);
    float4 a00 = ap0[0], a01 = ap0[1];
    float4 a10 = ap1[0], a11 = ap1[1];
    half8 af0, af1;
    af0[0]=(_Float16)a00.x; af0[1]=(_Float16)a00.y; af0[2]=(_Float16)a00.z; af0[3]=(_Float16)a00.w;
    af0[4]=(_Float16)a01.x; af0[5]=(_Float16)a01.y; af0[6]=(_Float16)a01.z; af0[7]=(_Float16)a01.w;
    af1[0]=(_Float16)a10.x; af1[1]=(_Float16)a10.y; af1[2]=(_Float16)a10.z; af1[3]=(_Float16)a10.w;
    af1[4]=(_Float16)a11.x; af1[5]=(_Float16)a11.y; af1[6]=(_Float16)a11.z; af1[7]=(_Float16)a11.w;

    const _Float16* bchunk = W1p + kk * (256*32);
    #pragma unroll
    for (int nt = 0; nt < 16; nt++){
      half8 bf = *(const half8*)(bchunk + (nt*16 + l16) * 32 + quad * 8);
      acc0[nt] = __builtin_amdgcn_mfma_f32_16x16x32_f16(af0, bf, acc0[nt], 0, 0, 0);
      acc1[nt] = __builtin_amdgcn_mfma_f32_16x16x32_f16(af1, bf, acc1[nt], 0, 0, 0);
    }
  }
  #pragma unroll
  for (int nt = 0; nt < 16; nt++){
    int s = nt >> 1;                          // slice = col/32
    _Float16* base = XW1s + (size_t)s * NN * 32 + (nt & 1) * 16 + l16;
    #pragma unroll
    for (int r = 0; r < 4; r++){
      int row0 = m0 + quad*4 + r;
      int row1 = m0 + 16 + quad*4 + r;
      if (row0 < NN) base[(size_t)row0 * 32] = (_Float16)acc0[nt][r];
      if (row1 < NN) base[(size_t)row1 * 32] = (_Float16)acc1[nt][r];
    }
  }
}

// ---- SpMM1 + ReLU + dropout, XCD-sliced, f16 dot2: block b -> slice b&7.
// ---- wave = 4 rows x 4 edge-grps x 4 q-lanes(16B). 2 edges paired per dot2.
__global__ __launch_bounds__(256) void k_spmm1(const int* __restrict__ row_ptr,
                                               const int* __restrict__ a_col,
                                               const float* __restrict__ a_val,
                                               const _Float16* __restrict__ XW1s,
                                               const int* __restrict__ drop_mask,
                                               _Float16* __restrict__ hb){
  int s  = blockIdx.x & 7;                 // slice == XCD (blocks round-robin XCDs)
  int rg = blockIdx.x >> 3;                // 16 rows/block
  int wave = threadIdx.x >> 6, lane = threadIdx.x & 63;
  int row_local = lane >> 4;
  int grp = (lane >> 2) & 3;
  int q   = lane & 3;
  int r = rg * 16 + wave * 4 + row_local;
  int es = row_ptr[r], ee = row_ptr[r+1];
  const _Float16* Xs = XW1s + (size_t)s * NN * 32 + q * 8;

  float acc[8] = {0,0,0,0,0,0,0,0};
  int i = es + grp;
  for (; i + 4 < ee; i += 8){              // edges i and i+4, paired
    float v0 = a_val[i];     int c0 = a_col[i];
    float v1 = a_val[i+4];   int c1 = a_col[i+4];
    int4 x0 = *(const int4*)(Xs + (size_t)c0 * 32);
    int4 x1 = *(const int4*)(Xs + (size_t)c1 * 32);
#if HAS_DOT2
    half2v vv = { (_Float16)v0, (_Float16)v1 };
    const int xs0[4] = {x0.x, x0.y, x0.z, x0.w};
    const int xs1[4] = {x1.x, x1.y, x1.z, x1.w};
    #pragma unroll
    for (int d = 0; d < 4; d++){
      int lo = __builtin_amdgcn_perm(xs1[d], xs0[d], 0x05040100);  // {e0.lo, e1.lo}
      int hi = __builtin_amdgcn_perm(xs1[d], xs0[d], 0x07060302);  // {e0.hi, e1.hi}
      acc[2*d]   = __builtin_amdgcn_fdot2(__builtin_bit_cast(half2v, lo), vv, acc[2*d],   false);
      acc[2*d+1] = __builtin_amdgcn_fdot2(__builtin_bit_cast(half2v, hi), vv, acc[2*d+1], false);
    }
#else
    const int xs0[4] = {x0.x, x0.y, x0.z, x0.w};
    const int xs1[4] = {x1.x, x1.y, x1.z, x1.w};
    #pragma unroll
    for (int d = 0; d < 4; d++){
      half2v h0 = __builtin_bit_cast(half2v, xs0[d]);
      half2v h1 = __builtin_bit_cast(half2v, xs1[d]);
      acc[2*d]   += v0 * (float)h0.x + v1 * (float)h1.x;
      acc[2*d+1] += v0 * (float)h0.y + v1 * (float)h1.y;
    }
#endif
  }
  for (; i < ee; i += 4){                  // tail: single edge
    float v = a_val[i];  int c = a_col[i];
    int4 x = *(const int4*)(Xs + (size_t)c * 32);
    const int xs[4] = {x.x, x.y, x.z, x.w};
    #pragma unroll
    for (int d = 0; d < 4; d++){
      half2v h = __builtin_bit_cast(half2v, xs[d]);
      acc[2*d]   += v * (float)h.x;
      acc[2*d+1] += v * (float)h.y;
    }
  }
  #pragma unroll
  for (int j = 0; j < 8; j++){             // reduce over the 4 edge groups
    acc[j] += __shfl_xor(acc[j], 4);
    acc[j] += __shfl_xor(acc[j], 8);
  }
  if (grp == 0){                           // lanes q=0..3 of each row write 16B
    const int* dm = drop_mask + (size_t)r * HIDF + s * 32 + q * 8;
    int4 d0 = *(const int4*)(dm);
    int4 d1 = *(const int4*)(dm + 4);
    half8 o;
    o[0] = (_Float16)(fmaxf(acc[0],0.f) * (float)d0.x * 2.0f);
    o[1] = (_Float16)(fmaxf(acc[1],0.f) * (float)d0.y * 2.0f);
    o[2] = (_Float16)(fmaxf(acc[2],0.f) * (float)d0.z * 2.0f);
    o[3] = (_Float16)(fmaxf(acc[3],0.f) * (float)d0.w * 2.0f);
    o[4] = (_Float16)(fmaxf(acc[4],0.f) * (float)d1.x * 2.0f);
    o[5] = (_Float16)(fmaxf(acc[5],0.f) * (float)d1.y * 2.0f);
    o[6] = (_Float16)(fmaxf(acc[6],0.f) * (float)d1.z * 2.0f);
    o[7] = (_Float16)(fmaxf(acc[7],0.f) * (float)d1.w * 2.0f);
    *(half8*)(hb + (size_t)r * HIDF + s * 32 + q * 8) = o;
  }
}

// -------- GEMM2: HW2s (4-sliced f16) = h[NN,HIDF] @ W2; slice = nt --------
__global__ __launch_bounds__(256) void k_gemm2(const _Float16* __restrict__ A,  // hb
                                               const _Float16* __restrict__ BT, // [64][256]
                                               _Float16* __restrict__ HW2s){
  int wave = threadIdx.x >> 6, lane = threadIdx.x & 63;
  int tile_m = blockIdx.x * 4 + wave;
  if (tile_m >= MTILES) return;
  int m0 = tile_m * 16, l16 = lane & 15, quad = lane >> 4;

  f32x4 acc[4];
  #pragma unroll
  for (int t = 0; t < 4; t++) acc[t] = (f32x4){0.f,0.f,0.f,0.f};

  const _Float16* ar = A + (size_t)(m0 + l16) * HIDF + quad * 8;
  for (int kk = 0; kk < HIDF/32; kk++){
    half8 af = *(const half8*)(ar + kk * 32);
    #pragma unroll
    for (int nt = 0; nt < 4; nt++){
      half8 bf = *(const half8*)(BT + (size_t)(nt*16 + l16) * HIDF + kk*32 + quad*8);
      acc[nt] = __builtin_amdgcn_mfma_f32_16x16x32_f16(af, bf, acc[nt], 0, 0, 0);
    }
  }
  #pragma unroll
  for (int nt = 0; nt < 4; nt++){          // slice nt: contiguous [NN][16] (1.6MB)
    _Float16* base = HW2s + (size_t)nt * NN * 16 + l16;
    #pragma unroll
    for (int r = 0; r < 4; r++)
      base[(size_t)(m0 + quad*4 + r) * 16] = (_Float16)acc[nt][r];
  }
}

// -- SpMM2 raw scores, XCD-sliced f16 dot2: slice = blockIdx&3 (4 | 8). --
__global__ __launch_bounds__(256) void k_spmm2(const int* __restrict__ row_ptr,
                                               const int* __restrict__ a_col,
                                               const float* __restrict__ a_val,
                                               const _Float16* __restrict__ HW2s,
                                               float* __restrict__ out){
  int t  = blockIdx.x & 3;                 // slice of 16 classes
  int rg = blockIdx.x >> 2;                // 16 rows/block
  int wave = threadIdx.x >> 6, lane = threadIdx.x & 63;
  int row_local = lane >> 4;
  int grp = (lane >> 2) & 3;
  int q   = lane & 3;                      // 4 lanes x 8B cover the 32B slice entry
  int r = rg * 16 + wave * 4 + row_local;
  int es = row_ptr[r], ee = row_ptr[r+1];
  const _Float16* Hs = HW2s + (size_t)t * NN * 16 + q * 4;

  float acc[4] = {0,0,0,0};
  int i = es + grp;
  for (; i + 4 < ee; i += 8){
    float v0 = a_val[i];     int c0 = a_col[i];
    float v1 = a_val[i+4];   int c1 = a_col[i+4];
    int2 x0 = *(const int2*)(Hs + (size_t)c0 * 16);
    int2 x1 = *(const int2*)(Hs + (size_t)c1 * 16);
#if HAS_DOT2
    half2v vv = { (_Float16)v0, (_Float16)v1 };
    const int xs0[2] = {x0.x, x0.y};
    const int xs1[2] = {x1.x, x1.y};
    #pragma unroll
    for (int d = 0; d < 2; d++){
      int lo = __builtin_amdgcn_perm(xs1[d], xs0[d], 0x05040100);
      int hi = __builtin_amdgcn_perm(xs1[d], xs0[d], 0x07060302);
      acc[2*d]   = __builtin_amdgcn_fdot2(__builtin_bit_cast(half2v, lo), vv, acc[2*d],   false);
      acc[2*d+1] = __builtin_amdgcn_fdot2(__builtin_bit_cast(half2v, hi), vv, acc[2*d+1], false);
    }
#else
    const int xs0[2] = {x0.x, x0.y};
    const int xs1[2] = {x1.x, x1.y};
    #pragma unroll
    for (int d = 0; d < 2; d++){
      half2v h0 = __builtin_bit_cast(half2v, xs0[d]);
      half2v h1 = __builtin_bit_cast(half2v, xs1[d]);
      acc[2*d]   += v0 * (float)h0.x + v1 * (float)h1.x;
      acc[2*d+1] += v0 * (float)h0.y + v1 * (float)h1.y;
    }
#endif
  }
  for (; i < ee; i += 4){
    float v = a_val[i];  int c = a_col[i];
    int2 x = *(const int2*)(Hs + (size_t)c * 16);
    const int xs[2] = {x.x, x.y};
    #pragma unroll
    for (int d = 0; d < 2; d++){
      half2v h = __builtin_bit_cast(half2v, xs[d]);
      acc[2*d]   += v * (float)h.x;
      acc[2*d+1] += v * (float)h.y;
    }
  }
  #pragma unroll
  for (int j = 0; j < 4; j++){
    acc[j] += __shfl_xor(acc[j], 4);
    acc[j] += __shfl_xor(acc[j], 8);
  }
  if (grp == 0){
    float4 o4 = { acc[0], acc[1], acc[2], acc[3] };
    *(float4*)(out + (size_t)r * OUTF + t * 16 + q * 4) = o4;
  }
}

// ---- log_softmax in-place on out: wave = 1 row (64 classes = 64 lanes) ----
__global__ __launch_bounds__(256) void k_lsm(float* __restrict__ out){
  int wave = threadIdx.x >> 6, lane = threadIdx.x & 63;
  int r = blockIdx.x * 4 + wave;
  float x = out[(size_t)r * OUTF + lane];
  float m = x;
  #pragma unroll
  for (int o = 1; o <= 32; o <<= 1) m = fmaxf(m, __shfl_xor(m, o));
  float ssum = expf(x - m);
  #pragma unroll
  for (int o = 1; o <= 32; o <<= 1) ssum += __shfl_xor(ssum, o);
  out[(size_t)r * OUTF + lane] = x - m - logf(ssum);
}

extern "C" void kernel_launch(void* const* d_in, const int* in_sizes, int n_in,
                              void* d_out, int out_size, void* d_ws, size_t ws_size,
                              hipStream_t stream) {
  const float* X      = (const float*)d_in[0];
  const float* W1     = (const float*)d_in[1];
  const float* W2     = (const float*)d_in[2];
  const int*   a_row  = (const int*)d_in[3];
  const int*   a_col  = (const int*)d_in[4];
  const float* a_val  = (const float*)d_in[5];
  const int*   drop   = (const int*)d_in[6];
  float*       out    = (float*)d_out;

  char* ws = (char*)d_ws;
  int*       row_ptr = (int*)      (ws);                 //   200,704 B
  _Float16*  W1p     = (_Float16*)(ws + 200704);         //   262,144 B
  _Float16*  W2T     = (_Float16*)(ws + 462848);         //    32,768 B
  _Float16*  XW1s    = (_Float16*)(ws + 495616);         // 25,600,000 B (8 slices)
  _Float16*  hb      = (_Float16*)(ws + 26095616);       // 25,600,000 B
  _Float16*  HW2s    = (_Float16*)(ws + 51695616);       //  6,400,000 B (4 slices)

  k_prep<<<772, 256, 0, stream>>>(a_row, row_ptr, W1, W1p, W2, W2T);
  k_gemm1<<<(NN + 63)/64, 128, 0, stream>>>(X, W1p, XW1s);
  k_spmm1<<<8 * (NN/16), 256, 0, stream>>>(row_ptr, a_col, a_val, XW1s, drop, hb);
  k_gemm2<<<(MTILES + 3)/4, 256, 0, stream>>>(hb, W2T, HW2s);
  k_spmm2<<<4 * (NN/16), 256, 0, stream>>>(row_ptr, a_col, a_val, HW2s, out);
  k_lsm<<<NN/4, 256, 0, stream>>>(out);
}

// Round 7
// 368.692 us; speedup vs baseline: 1.0636x; 1.0636x over previous
//
#include <hip/hip_runtime.h>
#include <hip/hip_fp16.h>
#include <math.h>

#define NN   50000
#define EE   800000
#define INF  512
#define HIDF 256
#define OUTF 64
#define MTILES (NN/16)   // 3125

using half8  = __attribute__((ext_vector_type(8))) _Float16;
using half2v = __attribute__((ext_vector_type(2))) _Float16;
using f32x4  = __attribute__((ext_vector_type(4))) float;

#if __has_builtin(__builtin_amdgcn_fdot2)
#define HAS_DOT2 1
#else
#define HAS_DOT2 0
#endif

// ---- fused prep: row_ptr (blocks 0..195) | W1 pack (196..707) | W2^T (708..771) ----
__global__ void k_prep(const int* __restrict__ a_row, int* __restrict__ row_ptr,
                       const float* __restrict__ W1, _Float16* __restrict__ W1p,
                       const float* __restrict__ W2, _Float16* __restrict__ W2T){
  int b = blockIdx.x, tid = threadIdx.x;
  if (b < 196){
    int i = b * 256 + tid;
    if (i > NN) return;
    int lo = 0, hi = EE;
    while (lo < hi){ int mid = (lo + hi) >> 1; if (a_row[mid] < i) lo = mid + 1; else hi = mid; }
    row_ptr[i] = lo;
  } else if (b < 708){
    int idx = (b - 196) * 256 + tid;        // 512*256 elements
    int k = idx >> 8, col = idx & 255;
    int kk = k >> 5, k2 = k & 31;
    W1p[((kk << 8) + col) * 32 + k2] = (_Float16)W1[idx];
  } else {
    int idx = (b - 708) * 256 + tid;        // 256*64 elements
    int k = idx >> 6, n = idx & 63;
    W2T[n * HIDF + k] = (_Float16)W2[idx];
  }
}

// ---------------- GEMM1: XW1s (8-sliced f16) = X[NN,INF] @ W1 ----------------
// wave = 16 rows x 256 cols (16 acc = 64 VGPR), barrier-free, B from global L2.
// launch_bounds(256,4): cap 128 VGPR -> 4 waves/SIMD; grid = 3125 waves.
__global__ __launch_bounds__(256, 4) void k_gemm1(const float* __restrict__ X,
                                                  const _Float16* __restrict__ W1p,
                                                  _Float16* __restrict__ XW1s){
  int wave = threadIdx.x >> 6, lane = threadIdx.x & 63;
  int l16 = lane & 15, quad = lane >> 4;
  int tile = blockIdx.x * 4 + wave;          // 3125 tiles of 16 rows
  if (tile >= MTILES) return;
  int m0 = tile * 16;
  const float* arow = X + (size_t)(m0 + l16) * INF + quad * 8;

  f32x4 acc[16];
  #pragma unroll
  for (int t = 0; t < 16; t++) acc[t] = (f32x4){0.f,0.f,0.f,0.f};

  for (int kk = 0; kk < INF/32; kk++){
    const float4* ap = (const float4*)(arow + kk * 32);
    float4 a0 = ap[0], a1 = ap[1];
    half8 af;
    af[0]=(_Float16)a0.x; af[1]=(_Float16)a0.y; af[2]=(_Float16)a0.z; af[3]=(_Float16)a0.w;
    af[4]=(_Float16)a1.x; af[5]=(_Float16)a1.y; af[6]=(_Float16)a1.z; af[7]=(_Float16)a1.w;

    const _Float16* bchunk = W1p + kk * (256*32);
    #pragma unroll
    for (int nt = 0; nt < 16; nt++){
      half8 bf = *(const half8*)(bchunk + (nt*16 + l16) * 32 + quad * 8);
      acc[nt] = __builtin_amdgcn_mfma_f32_16x16x32_f16(af, bf, acc[nt], 0, 0, 0);
    }
  }
  #pragma unroll
  for (int nt = 0; nt < 16; nt++){
    int s = nt >> 1;                          // slice = col/32
    _Float16* base = XW1s + (size_t)s * NN * 32 + (nt & 1) * 16 + l16;
    #pragma unroll
    for (int r = 0; r < 4; r++)
      base[(size_t)(m0 + quad*4 + r) * 32] = (_Float16)acc[nt][r];
  }
}

// ---- SpMM1 + ReLU + dropout, XCD-sliced, f16 dot2: block b -> slice b&7.
// ---- wave = 4 rows x 4 edge-grps x 4 q-lanes(16B). 2 edges paired per dot2.
__global__ __launch_bounds__(256) void k_spmm1(const int* __restrict__ row_ptr,
                                               const int* __restrict__ a_col,
                                               const float* __restrict__ a_val,
                                               const _Float16* __restrict__ XW1s,
                                               const int* __restrict__ drop_mask,
                                               _Float16* __restrict__ hb){
  int s  = blockIdx.x & 7;                 // slice == XCD (blocks round-robin XCDs)
  int rg = blockIdx.x >> 3;                // 16 rows/block
  int wave = threadIdx.x >> 6, lane = threadIdx.x & 63;
  int row_local = lane >> 4;
  int grp = (lane >> 2) & 3;
  int q   = lane & 3;
  int r = rg * 16 + wave * 4 + row_local;
  int es = row_ptr[r], ee = row_ptr[r+1];
  const _Float16* Xs = XW1s + (size_t)s * NN * 32 + q * 8;

  float acc[8] = {0,0,0,0,0,0,0,0};
  int i = es + grp;
  for (; i + 4 < ee; i += 8){              // edges i and i+4, paired
    float v0 = a_val[i];     int c0 = a_col[i];
    float v1 = a_val[i+4];   int c1 = a_col[i+4];
    int4 x0 = *(const int4*)(Xs + (size_t)c0 * 32);
    int4 x1 = *(const int4*)(Xs + (size_t)c1 * 32);
#if HAS_DOT2
    half2v vv = { (_Float16)v0, (_Float16)v1 };
    const int xs0[4] = {x0.x, x0.y, x0.z, x0.w};
    const int xs1[4] = {x1.x, x1.y, x1.z, x1.w};
    #pragma unroll
    for (int d = 0; d < 4; d++){
      int lo = __builtin_amdgcn_perm(xs1[d], xs0[d], 0x05040100);  // {e0.lo, e1.lo}
      int hi = __builtin_amdgcn_perm(xs1[d], xs0[d], 0x07060302);  // {e0.hi, e1.hi}
      acc[2*d]   = __builtin_amdgcn_fdot2(__builtin_bit_cast(half2v, lo), vv, acc[2*d],   false);
      acc[2*d+1] = __builtin_amdgcn_fdot2(__builtin_bit_cast(half2v, hi), vv, acc[2*d+1], false);
    }
#else
    const int xs0[4] = {x0.x, x0.y, x0.z, x0.w};
    const int xs1[4] = {x1.x, x1.y, x1.z, x1.w};
    #pragma unroll
    for (int d = 0; d < 4; d++){
      half2v h0 = __builtin_bit_cast(half2v, xs0[d]);
      half2v h1 = __builtin_bit_cast(half2v, xs1[d]);
      acc[2*d]   += v0 * (float)h0.x + v1 * (float)h1.x;
      acc[2*d+1] += v0 * (float)h0.y + v1 * (float)h1.y;
    }
#endif
  }
  for (; i < ee; i += 4){                  // tail: single edge
    float v = a_val[i];  int c = a_col[i];
    int4 x = *(const int4*)(Xs + (size_t)c * 32);
    const int xs[4] = {x.x, x.y, x.z, x.w};
    #pragma unroll
    for (int d = 0; d < 4; d++){
      half2v h = __builtin_bit_cast(half2v, xs[d]);
      acc[2*d]   += v * (float)h.x;
      acc[2*d+1] += v * (float)h.y;
    }
  }
  #pragma unroll
  for (int j = 0; j < 8; j++){             // reduce over the 4 edge groups
    acc[j] += __shfl_xor(acc[j], 4);
    acc[j] += __shfl_xor(acc[j], 8);
  }
  if (grp == 0){                           // lanes q=0..3 of each row write 16B
    const int* dm = drop_mask + (size_t)r * HIDF + s * 32 + q * 8;
    int4 d0 = *(const int4*)(dm);
    int4 d1 = *(const int4*)(dm + 4);
    half8 o;
    o[0] = (_Float16)(fmaxf(acc[0],0.f) * (float)d0.x * 2.0f);
    o[1] = (_Float16)(fmaxf(acc[1],0.f) * (float)d0.y * 2.0f);
    o[2] = (_Float16)(fmaxf(acc[2],0.f) * (float)d0.z * 2.0f);
    o[3] = (_Float16)(fmaxf(acc[3],0.f) * (float)d0.w * 2.0f);
    o[4] = (_Float16)(fmaxf(acc[4],0.f) * (float)d1.x * 2.0f);
    o[5] = (_Float16)(fmaxf(acc[5],0.f) * (float)d1.y * 2.0f);
    o[6] = (_Float16)(fmaxf(acc[6],0.f) * (float)d1.z * 2.0f);
    o[7] = (_Float16)(fmaxf(acc[7],0.f) * (float)d1.w * 2.0f);
    *(half8*)(hb + (size_t)r * HIDF + s * 32 + q * 8) = o;
  }
}

// -------- GEMM2: HW2[NN,OUTF](f16, row-major) = h[NN,HIDF] @ W2 --------
__global__ __launch_bounds__(256) void k_gemm2(const _Float16* __restrict__ A,  // hb
                                               const _Float16* __restrict__ BT, // [64][256]
                                               _Float16* __restrict__ HW2){
  int wave = threadIdx.x >> 6, lane = threadIdx.x & 63;
  int tile_m = blockIdx.x * 4 + wave;
  if (tile_m >= MTILES) return;
  int m0 = tile_m * 16, l16 = lane & 15, quad = lane >> 4;

  f32x4 acc[4];
  #pragma unroll
  for (int t = 0; t < 4; t++) acc[t] = (f32x4){0.f,0.f,0.f,0.f};

  const _Float16* ar = A + (size_t)(m0 + l16) * HIDF + quad * 8;
  for (int kk = 0; kk < HIDF/32; kk++){
    half8 af = *(const half8*)(ar + kk * 32);
    #pragma unroll
    for (int nt = 0; nt < 4; nt++){
      half8 bf = *(const half8*)(BT + (size_t)(nt*16 + l16) * HIDF + kk*32 + quad*8);
      acc[nt] = __builtin_amdgcn_mfma_f32_16x16x32_f16(af, bf, acc[nt], 0, 0, 0);
    }
  }
  #pragma unroll
  for (int nt = 0; nt < 4; nt++){
    int col = nt*16 + l16;
    #pragma unroll
    for (int r = 0; r < 4; r++)
      HW2[(size_t)(m0 + quad*4 + r) * OUTF + col] = (_Float16)acc[nt][r];
  }
}

// -- SpMM2 + fused log_softmax: wave = 1 row, 8 edge-grps x 8 lanes x 16B,
// -- x2 unroll = 16 gathers in flight, dot2 MACs. HW2 = 6.4MB (L2/L3-resident).
__global__ __launch_bounds__(256) void k_spmm2_lsm(const int* __restrict__ row_ptr,
                                                   const int* __restrict__ a_col,
                                                   const float* __restrict__ a_val,
                                                   const _Float16* __restrict__ HW2,
                                                   float* __restrict__ out){
  int wave = threadIdx.x >> 6, lane = threadIdx.x & 63;
  int r = blockIdx.x * 4 + wave;
  int s = row_ptr[r], e = row_ptr[r+1];
  int g = lane >> 3;          // 8 edge groups
  int q = lane & 7;           // lane covers classes q*8 .. q*8+7 (16B)
  float acc[8] = {0,0,0,0,0,0,0,0};

  int i = s + g;
  for (; i + 8 < e; i += 16){
    float v0 = a_val[i];     int c0 = a_col[i];
    float v1 = a_val[i+8];   int c1 = a_col[i+8];
    int4 x0 = *(const int4*)(HW2 + (size_t)c0 * OUTF + q * 8);
    int4 x1 = *(const int4*)(HW2 + (size_t)c1 * OUTF + q * 8);
#if HAS_DOT2
    half2v vv = { (_Float16)v0, (_Float16)v1 };
    const int xs0[4] = {x0.x, x0.y, x0.z, x0.w};
    const int xs1[4] = {x1.x, x1.y, x1.z, x1.w};
    #pragma unroll
    for (int d = 0; d < 4; d++){
      int lo = __builtin_amdgcn_perm(xs1[d], xs0[d], 0x05040100);
      int hi = __builtin_amdgcn_perm(xs1[d], xs0[d], 0x07060302);
      acc[2*d]   = __builtin_amdgcn_fdot2(__builtin_bit_cast(half2v, lo), vv, acc[2*d],   false);
      acc[2*d+1] = __builtin_amdgcn_fdot2(__builtin_bit_cast(half2v, hi), vv, acc[2*d+1], false);
    }
#else
    const int xs0[4] = {x0.x, x0.y, x0.z, x0.w};
    const int xs1[4] = {x1.x, x1.y, x1.z, x1.w};
    #pragma unroll
    for (int d = 0; d < 4; d++){
      half2v h0 = __builtin_bit_cast(half2v, xs0[d]);
      half2v h1 = __builtin_bit_cast(half2v, xs1[d]);
      acc[2*d]   += v0 * (float)h0.x + v1 * (float)h1.x;
      acc[2*d+1] += v0 * (float)h0.y + v1 * (float)h1.y;
    }
#endif
  }
  for (; i < e; i += 8){
    float v = a_val[i];  int c = a_col[i];
    int4 x = *(const int4*)(HW2 + (size_t)c * OUTF + q * 8);
    const int xs[4] = {x.x, x.y, x.z, x.w};
    #pragma unroll
    for (int d = 0; d < 4; d++){
      half2v h = __builtin_bit_cast(half2v, xs[d]);
      acc[2*d]   += v * (float)h.x;
      acc[2*d+1] += v * (float)h.y;
    }
  }
  #pragma unroll
  for (int j = 0; j < 8; j++){             // reduce over the 8 edge groups
    acc[j] += __shfl_xor(acc[j], 8);
    acc[j] += __shfl_xor(acc[j], 16);
    acc[j] += __shfl_xor(acc[j], 32);
  }
  // fused log_softmax over 64 classes (spread across q = lane&7, valid in g==0)
  float m = acc[0];
  #pragma unroll
  for (int j = 1; j < 8; j++) m = fmaxf(m, acc[j]);
  #pragma unroll
  for (int o = 1; o <= 4; o <<= 1) m = fmaxf(m, __shfl_xor(m, o));
  float ssum = 0.f;
  #pragma unroll
  for (int j = 0; j < 8; j++) ssum += expf(acc[j] - m);
  #pragma unroll
  for (int o = 1; o <= 4; o <<= 1) ssum += __shfl_xor(ssum, o);
  float ls = m + logf(ssum);
  if (g == 0){
    float4 o0 = { acc[0]-ls, acc[1]-ls, acc[2]-ls, acc[3]-ls };
    float4 o1 = { acc[4]-ls, acc[5]-ls, acc[6]-ls, acc[7]-ls };
    float* op = out + (size_t)r * OUTF + q * 8;
    *(float4*)(op)     = o0;
    *(float4*)(op + 4) = o1;
  }
}

extern "C" void kernel_launch(void* const* d_in, const int* in_sizes, int n_in,
                              void* d_out, int out_size, void* d_ws, size_t ws_size,
                              hipStream_t stream) {
  const float* X      = (const float*)d_in[0];
  const float* W1     = (const float*)d_in[1];
  const float* W2     = (const float*)d_in[2];
  const int*   a_row  = (const int*)d_in[3];
  const int*   a_col  = (const int*)d_in[4];
  const float* a_val  = (const float*)d_in[5];
  const int*   drop   = (const int*)d_in[6];
  float*       out    = (float*)d_out;

  char* ws = (char*)d_ws;
  int*       row_ptr = (int*)      (ws);                 //   200,704 B
  _Float16*  W1p     = (_Float16*)(ws + 200704);         //   262,144 B
  _Float16*  W2T     = (_Float16*)(ws + 462848);         //    32,768 B
  _Float16*  XW1s    = (_Float16*)(ws + 495616);         // 25,600,000 B (8 slices)
  _Float16*  hb      = (_Float16*)(ws + 26095616);       // 25,600,000 B
  _Float16*  HW2     = (_Float16*)(ws + 51695616);       //  6,400,000 B

  k_prep<<<772, 256, 0, stream>>>(a_row, row_ptr, W1, W1p, W2, W2T);
  k_gemm1<<<(MTILES + 3)/4, 256, 0, stream>>>(X, W1p, XW1s);
  k_spmm1<<<8 * (NN/16), 256, 0, stream>>>(row_ptr, a_col, a_val, XW1s, drop, hb);
  k_gemm2<<<(MTILES + 3)/4, 256, 0, stream>>>(hb, W2T, HW2);
  k_spmm2_lsm<<<NN/4, 256, 0, stream>>>(row_ptr, a_col, a_val, HW2, out);
}

// Round 8
// 361.257 us; speedup vs baseline: 1.0855x; 1.0206x over previous
//
#include <hip/hip_runtime.h>
#include <hip/hip_fp16.h>
#include <math.h>

#define NN   50000
#define EE   800000
#define INF  512
#define HIDF 256
#define OUTF 64
#define MTILES (NN/16)   // 3125

using half8  = __attribute__((ext_vector_type(8))) _Float16;
using half2v = __attribute__((ext_vector_type(2))) _Float16;
using f32x4  = __attribute__((ext_vector_type(4))) float;

#if __has_builtin(__builtin_amdgcn_fdot2)
#define HAS_DOT2 1
#else
#define HAS_DOT2 0
#endif

// ---- fused prep: row_ptr | W1 pack | W2^T | edge pack {col,val} ----
__global__ void k_prep(const int* __restrict__ a_row, int* __restrict__ row_ptr,
                       const float* __restrict__ W1, _Float16* __restrict__ W1p,
                       const float* __restrict__ W2, _Float16* __restrict__ W2T,
                       const int* __restrict__ a_col, const float* __restrict__ a_val,
                       int2* __restrict__ epk){
  int b = blockIdx.x, tid = threadIdx.x;
  if (b < 196){
    int i = b * 256 + tid;
    if (i > NN) return;
    int lo = 0, hi = EE;
    while (lo < hi){ int mid = (lo + hi) >> 1; if (a_row[mid] < i) lo = mid + 1; else hi = mid; }
    row_ptr[i] = lo;
  } else if (b < 708){
    int idx = (b - 196) * 256 + tid;        // 512*256 elements
    int k = idx >> 8, col = idx & 255;
    int kk = k >> 5, k2 = k & 31;
    W1p[((kk << 8) + col) * 32 + k2] = (_Float16)W1[idx];
  } else if (b < 772){
    int idx = (b - 708) * 256 + tid;        // 256*64 elements
    int k = idx >> 6, n = idx & 63;
    W2T[n * HIDF + k] = (_Float16)W2[idx];
  } else {
    int idx = (b - 772) * 256 + tid;        // E elements (3125*256 == E)
    int2 e; e.x = a_col[idx]; e.y = __builtin_bit_cast(int, a_val[idx]);
    epk[idx] = e;
  }
}

// ---------------- GEMM1: XW1s (8-sliced f16) = X[NN,INF] @ W1 ----------------
// wave = 16 rows x 256 cols (16 acc = 64 VGPR), barrier-free, B from global L2.
__global__ __launch_bounds__(256, 4) void k_gemm1(const float* __restrict__ X,
                                                  const _Float16* __restrict__ W1p,
                                                  _Float16* __restrict__ XW1s){
  int wave = threadIdx.x >> 6, lane = threadIdx.x & 63;
  int l16 = lane & 15, quad = lane >> 4;
  int tile = blockIdx.x * 4 + wave;          // 3125 tiles of 16 rows
  if (tile >= MTILES) return;
  int m0 = tile * 16;
  const float* arow = X + (size_t)(m0 + l16) * INF + quad * 8;

  f32x4 acc[16];
  #pragma unroll
  for (int t = 0; t < 16; t++) acc[t] = (f32x4){0.f,0.f,0.f,0.f};

  for (int kk = 0; kk < INF/32; kk++){
    const float4* ap = (const float4*)(arow + kk * 32);
    float4 a0 = ap[0], a1 = ap[1];
    half8 af;
    af[0]=(_Float16)a0.x; af[1]=(_Float16)a0.y; af[2]=(_Float16)a0.z; af[3]=(_Float16)a0.w;
    af[4]=(_Float16)a1.x; af[5]=(_Float16)a1.y; af[6]=(_Float16)a1.z; af[7]=(_Float16)a1.w;

    const _Float16* bchunk = W1p + kk * (256*32);
    #pragma unroll
    for (int nt = 0; nt < 16; nt++){
      half8 bf = *(const half8*)(bchunk + (nt*16 + l16) * 32 + quad * 8);
      acc[nt] = __builtin_amdgcn_mfma_f32_16x16x32_f16(af, bf, acc[nt], 0, 0, 0);
    }
  }
  #pragma unroll
  for (int nt = 0; nt < 16; nt++){
    int s = nt >> 1;                          // slice = col/32
    _Float16* base = XW1s + (size_t)s * NN * 32 + (nt & 1) * 16 + l16;
    #pragma unroll
    for (int r = 0; r < 4; r++)
      base[(size_t)(m0 + quad*4 + r) * 32] = (_Float16)acc[nt][r];
  }
}

// ---- SpMM1 + ReLU + dropout, XCD-sliced: wave = 16 rows x 4 lanes.
// ---- Each 4-lane group owns a whole row: NO reduction, 4-edge unroll,
// ---- 8B packed edge loads, 4 gathers in flight per lane.
__global__ __launch_bounds__(256) void k_spmm1(const int* __restrict__ row_ptr,
                                               const int2* __restrict__ epk,
                                               const _Float16* __restrict__ XW1s,
                                               const int* __restrict__ drop_mask,
                                               _Float16* __restrict__ hb){
  int s  = blockIdx.x & 7;                 // slice == XCD (blocks round-robin XCDs)
  int bg = blockIdx.x >> 3;                // 64 rows per block
  int lane = threadIdx.x & 63, wave = threadIdx.x >> 6;
  int rl = lane >> 2;                      // 16 rows per wave
  int q  = lane & 3;                       // 4 lanes x 16B = 64B slice entry
  int r = bg * 64 + wave * 16 + rl;
  bool valid = r < NN;
  int rc = valid ? r : NN - 1;
  int es = row_ptr[rc], ee = row_ptr[rc + 1];
  if (!valid) ee = es;
  const _Float16* Xs = XW1s + (size_t)s * NN * 32 + q * 8;

  float acc[8] = {0,0,0,0,0,0,0,0};
  int i = es;
  for (; i + 3 < ee; i += 4){
    int2 e0 = epk[i], e1 = epk[i+1], e2 = epk[i+2], e3 = epk[i+3];
    int4 x0 = *(const int4*)(Xs + (size_t)e0.x * 32);
    int4 x1 = *(const int4*)(Xs + (size_t)e1.x * 32);
    int4 x2 = *(const int4*)(Xs + (size_t)e2.x * 32);
    int4 x3 = *(const int4*)(Xs + (size_t)e3.x * 32);
    float v0 = __builtin_bit_cast(float, e0.y);
    float v1 = __builtin_bit_cast(float, e1.y);
    float v2 = __builtin_bit_cast(float, e2.y);
    float v3 = __builtin_bit_cast(float, e3.y);
#if HAS_DOT2
    half2v va = { (_Float16)v0, (_Float16)v1 };
    half2v vb = { (_Float16)v2, (_Float16)v3 };
    const int xs0[4] = {x0.x, x0.y, x0.z, x0.w};
    const int xs1[4] = {x1.x, x1.y, x1.z, x1.w};
    const int xs2[4] = {x2.x, x2.y, x2.z, x2.w};
    const int xs3[4] = {x3.x, x3.y, x3.z, x3.w};
    #pragma unroll
    for (int d = 0; d < 4; d++){
      int loa = __builtin_amdgcn_perm(xs1[d], xs0[d], 0x05040100);
      int hia = __builtin_amdgcn_perm(xs1[d], xs0[d], 0x07060302);
      int lob = __builtin_amdgcn_perm(xs3[d], xs2[d], 0x05040100);
      int hib = __builtin_amdgcn_perm(xs3[d], xs2[d], 0x07060302);
      acc[2*d]   = __builtin_amdgcn_fdot2(__builtin_bit_cast(half2v, loa), va, acc[2*d],   false);
      acc[2*d+1] = __builtin_amdgcn_fdot2(__builtin_bit_cast(half2v, hia), va, acc[2*d+1], false);
      acc[2*d]   = __builtin_amdgcn_fdot2(__builtin_bit_cast(half2v, lob), vb, acc[2*d],   false);
      acc[2*d+1] = __builtin_amdgcn_fdot2(__builtin_bit_cast(half2v, hib), vb, acc[2*d+1], false);
    }
#else
    const int xsA[4][4] = {{x0.x,x0.y,x0.z,x0.w},{x1.x,x1.y,x1.z,x1.w},
                           {x2.x,x2.y,x2.z,x2.w},{x3.x,x3.y,x3.z,x3.w}};
    const float vA[4] = {v0,v1,v2,v3};
    #pragma unroll
    for (int k = 0; k < 4; k++)
      #pragma unroll
      for (int d = 0; d < 4; d++){
        half2v h = __builtin_bit_cast(half2v, xsA[k][d]);
        acc[2*d]   += vA[k] * (float)h.x;
        acc[2*d+1] += vA[k] * (float)h.y;
      }
#endif
  }
  for (; i < ee; i++){                     // tail (<=3 edges)
    int2 e = epk[i];
    float v = __builtin_bit_cast(float, e.y);
    int4 x = *(const int4*)(Xs + (size_t)e.x * 32);
    const int xs[4] = {x.x, x.y, x.z, x.w};
    #pragma unroll
    for (int d = 0; d < 4; d++){
      half2v h = __builtin_bit_cast(half2v, xs[d]);
      acc[2*d]   += v * (float)h.x;
      acc[2*d+1] += v * (float)h.y;
    }
  }
  if (valid){
    const int* dm = drop_mask + (size_t)r * HIDF + s * 32 + q * 8;
    int4 d0 = *(const int4*)(dm);
    int4 d1 = *(const int4*)(dm + 4);
    half8 o;
    o[0] = (_Float16)(fmaxf(acc[0],0.f) * (float)d0.x * 2.0f);
    o[1] = (_Float16)(fmaxf(acc[1],0.f) * (float)d0.y * 2.0f);
    o[2] = (_Float16)(fmaxf(acc[2],0.f) * (float)d0.z * 2.0f);
    o[3] = (_Float16)(fmaxf(acc[3],0.f) * (float)d0.w * 2.0f);
    o[4] = (_Float16)(fmaxf(acc[4],0.f) * (float)d1.x * 2.0f);
    o[5] = (_Float16)(fmaxf(acc[5],0.f) * (float)d1.y * 2.0f);
    o[6] = (_Float16)(fmaxf(acc[6],0.f) * (float)d1.z * 2.0f);
    o[7] = (_Float16)(fmaxf(acc[7],0.f) * (float)d1.w * 2.0f);
    *(half8*)(hb + (size_t)r * HIDF + s * 32 + q * 8) = o;
  }
}

// -------- GEMM2: HW2[NN,OUTF](f16, row-major) = h[NN,HIDF] @ W2 --------
__global__ __launch_bounds__(256) void k_gemm2(const _Float16* __restrict__ A,  // hb
                                               const _Float16* __restrict__ BT, // [64][256]
                                               _Float16* __restrict__ HW2){
  int wave = threadIdx.x >> 6, lane = threadIdx.x & 63;
  int tile_m = blockIdx.x * 4 + wave;
  if (tile_m >= MTILES) return;
  int m0 = tile_m * 16, l16 = lane & 15, quad = lane >> 4;

  f32x4 acc[4];
  #pragma unroll
  for (int t = 0; t < 4; t++) acc[t] = (f32x4){0.f,0.f,0.f,0.f};

  const _Float16* ar = A + (size_t)(m0 + l16) * HIDF + quad * 8;
  for (int kk = 0; kk < HIDF/32; kk++){
    half8 af = *(const half8*)(ar + kk * 32);
    #pragma unroll
    for (int nt = 0; nt < 4; nt++){
      half8 bf = *(const half8*)(BT + (size_t)(nt*16 + l16) * HIDF + kk*32 + quad*8);
      acc[nt] = __builtin_amdgcn_mfma_f32_16x16x32_f16(af, bf, acc[nt], 0, 0, 0);
    }
  }
  #pragma unroll
  for (int nt = 0; nt < 4; nt++){
    int col = nt*16 + l16;
    #pragma unroll
    for (int r = 0; r < 4; r++)
      HW2[(size_t)(m0 + quad*4 + r) * OUTF + col] = (_Float16)acc[nt][r];
  }
}

// -- SpMM2 + fused log_softmax: wave = 8 rows x 8 lanes (16B = full 128B row),
// -- 4-edge unroll, no cross-row reduction; lsm via 3 shuffles in 8-lane group.
__global__ __launch_bounds__(256) void k_spmm2_lsm(const int* __restrict__ row_ptr,
                                                   const int2* __restrict__ epk,
                                                   const _Float16* __restrict__ HW2,
                                                   float* __restrict__ out){
  int lane = threadIdx.x & 63, wave = threadIdx.x >> 6;
  int rl = lane >> 3;                      // 8 rows per wave
  int q  = lane & 7;                       // lane covers classes q*8 .. q*8+7
  int r = blockIdx.x * 32 + wave * 8 + rl;
  bool valid = r < NN;
  int rc = valid ? r : NN - 1;
  int es = row_ptr[rc], ee = row_ptr[rc + 1];
  if (!valid) ee = es;
  const _Float16* Hs = HW2 + q * 8;

  float acc[8] = {0,0,0,0,0,0,0,0};
  int i = es;
  for (; i + 3 < ee; i += 4){
    int2 e0 = epk[i], e1 = epk[i+1], e2 = epk[i+2], e3 = epk[i+3];
    int4 x0 = *(const int4*)(Hs + (size_t)e0.x * OUTF);
    int4 x1 = *(const int4*)(Hs + (size_t)e1.x * OUTF);
    int4 x2 = *(const int4*)(Hs + (size_t)e2.x * OUTF);
    int4 x3 = *(const int4*)(Hs + (size_t)e3.x * OUTF);
    float v0 = __builtin_bit_cast(float, e0.y);
    float v1 = __builtin_bit_cast(float, e1.y);
    float v2 = __builtin_bit_cast(float, e2.y);
    float v3 = __builtin_bit_cast(float, e3.y);
#if HAS_DOT2
    half2v va = { (_Float16)v0, (_Float16)v1 };
    half2v vb = { (_Float16)v2, (_Float16)v3 };
    const int xs0[4] = {x0.x, x0.y, x0.z, x0.w};
    const int xs1[4] = {x1.x, x1.y, x1.z, x1.w};
    const int xs2[4] = {x2.x, x2.y, x2.z, x2.w};
    const int xs3[4] = {x3.x, x3.y, x3.z, x3.w};
    #pragma unroll
    for (int d = 0; d < 4; d++){
      int loa = __builtin_amdgcn_perm(xs1[d], xs0[d], 0x05040100);
      int hia = __builtin_amdgcn_perm(xs1[d], xs0[d], 0x07060302);
      int lob = __builtin_amdgcn_perm(xs3[d], xs2[d], 0x05040100);
      int hib = __builtin_amdgcn_perm(xs3[d], xs2[d], 0x07060302);
      acc[2*d]   = __builtin_amdgcn_fdot2(__builtin_bit_cast(half2v, loa), va, acc[2*d],   false);
      acc[2*d+1] = __builtin_amdgcn_fdot2(__builtin_bit_cast(half2v, hia), va, acc[2*d+1], false);
      acc[2*d]   = __builtin_amdgcn_fdot2(__builtin_bit_cast(half2v, lob), vb, acc[2*d],   false);
      acc[2*d+1] = __builtin_amdgcn_fdot2(__builtin_bit_cast(half2v, hib), vb, acc[2*d+1], false);
    }
#else
    const int xsA[4][4] = {{x0.x,x0.y,x0.z,x0.w},{x1.x,x1.y,x1.z,x1.w},
                           {x2.x,x2.y,x2.z,x2.w},{x3.x,x3.y,x3.z,x3.w}};
    const float vA[4] = {v0,v1,v2,v3};
    #pragma unroll
    for (int k = 0; k < 4; k++)
      #pragma unroll
      for (int d = 0; d < 4; d++){
        half2v h = __builtin_bit_cast(half2v, xsA[k][d]);
        acc[2*d]   += vA[k] * (float)h.x;
        acc[2*d+1] += vA[k] * (float)h.y;
      }
#endif
  }
  for (; i < ee; i++){
    int2 e = epk[i];
    float v = __builtin_bit_cast(float, e.y);
    int4 x = *(const int4*)(Hs + (size_t)e.x * OUTF);
    const int xs[4] = {x.x, x.y, x.z, x.w};
    #pragma unroll
    for (int d = 0; d < 4; d++){
      half2v h = __builtin_bit_cast(half2v, xs[d]);
      acc[2*d]   += v * (float)h.x;
      acc[2*d+1] += v * (float)h.y;
    }
  }
  // log_softmax over 64 classes spread across the 8-lane group
  float m = acc[0];
  #pragma unroll
  for (int j = 1; j < 8; j++) m = fmaxf(m, acc[j]);
  #pragma unroll
  for (int o = 1; o <= 4; o <<= 1) m = fmaxf(m, __shfl_xor(m, o));
  float ssum = 0.f;
  #pragma unroll
  for (int j = 0; j < 8; j++) ssum += expf(acc[j] - m);
  #pragma unroll
  for (int o = 1; o <= 4; o <<= 1) ssum += __shfl_xor(ssum, o);
  float ls = m + logf(ssum);
  if (valid){
    float4 o0 = { acc[0]-ls, acc[1]-ls, acc[2]-ls, acc[3]-ls };
    float4 o1 = { acc[4]-ls, acc[5]-ls, acc[6]-ls, acc[7]-ls };
    float* op = out + (size_t)r * OUTF + q * 8;
    *(float4*)(op)     = o0;
    *(float4*)(op + 4) = o1;
  }
}

extern "C" void kernel_launch(void* const* d_in, const int* in_sizes, int n_in,
                              void* d_out, int out_size, void* d_ws, size_t ws_size,
                              hipStream_t stream) {
  const float* X      = (const float*)d_in[0];
  const float* W1     = (const float*)d_in[1];
  const float* W2     = (const float*)d_in[2];
  const int*   a_row  = (const int*)d_in[3];
  const int*   a_col  = (const int*)d_in[4];
  const float* a_val  = (const float*)d_in[5];
  const int*   drop   = (const int*)d_in[6];
  float*       out    = (float*)d_out;

  char* ws = (char*)d_ws;
  int*       row_ptr = (int*)      (ws);                 //   200,704 B
  _Float16*  W1p     = (_Float16*)(ws + 200704);         //   262,144 B
  _Float16*  W2T     = (_Float16*)(ws + 462848);         //    32,768 B
  _Float16*  XW1s    = (_Float16*)(ws + 495616);         // 25,600,000 B (8 slices)
  _Float16*  hb      = (_Float16*)(ws + 26095616);       // 25,600,000 B
  _Float16*  HW2     = (_Float16*)(ws + 51695616);       //  6,400,000 B
  int2*      epk     = (int2*)    (ws + 58095616);       //  6,400,000 B (end ~64.5 MB)

  k_prep<<<3897, 256, 0, stream>>>(a_row, row_ptr, W1, W1p, W2, W2T, a_col, a_val, epk);
  k_gemm1<<<(MTILES + 3)/4, 256, 0, stream>>>(X, W1p, XW1s);
  k_spmm1<<<8 * ((NN + 63)/64), 256, 0, stream>>>(row_ptr, epk, XW1s, drop, hb);
  k_gemm2<<<(MTILES + 3)/4, 256, 0, stream>>>(hb, W2T, HW2);
  k_spmm2_lsm<<<(NN + 31)/32, 256, 0, stream>>>(row_ptr, epk, HW2, out);
}